// Round 4
// baseline (333.440 us; speedup 1.0000x reference)
//
#include <hip/hip_runtime.h>

typedef unsigned short ushort_t;
typedef unsigned int uint_t;
typedef __attribute__((ext_vector_type(8))) short short8;
typedef __attribute__((ext_vector_type(4))) float float4v;

#define STRIDE 264      // LDS activation leading dim (bf16 elems); keeps 16B row align
#define NLAT   2048
#define DLAT   64

// d_ws layout (ushort units): [0..127] flag area (int at byte 0), then packed weights
#define PW_BASE 128
#define PW0_OFF 0        // 7 ktiles * 16 nt * 64 lanes * 8 = 57344
#define PW1_OFF 57344    // 8 ktiles -> 65536 each
#define PW2_OFF 122880
#define PW3_OFF 188416

__device__ __forceinline__ float b2f(ushort_t u) {
  union { uint_t i; float f; } v; v.i = ((uint_t)u) << 16; return v.f;
}
__device__ __forceinline__ ushort_t f2b(float f) {
  uint_t x = __float_as_uint(f);
  uint_t r = (x + 0x7fffu + ((x >> 16) & 1u)) >> 16;   // RNE
  return (ushort_t)r;
}
__device__ __forceinline__ uint_t pack2(float lo, float hi) {
  return (uint_t)f2b(lo) | ((uint_t)f2b(hi) << 16);
}
__device__ __forceinline__ int imin(int a, int b) { return a < b ? a : b; }
__device__ __forceinline__ int imax(int a, int b) { return a > b ? a : b; }

// dtype-generic scalar load -> fp32
__device__ __forceinline__ float ldv(const float* p, long i)    { return p[i]; }
__device__ __forceinline__ float ldv(const ushort_t* p, long i) { return b2f(p[i]); }
// dtype-generic scalar store from fp32
__device__ __forceinline__ void stv(float* p, long i, float v)    { p[i] = v; }
__device__ __forceinline__ void stv(ushort_t* p, long i, float v) { p[i] = f2b(v); }

// ---------------------------------------------------------------------------
// lerp 8 consecutive elements from two rows, pack to bf16, one uint4 LDS store.
// ---------------------------------------------------------------------------
__device__ __forceinline__ void lerp8_store(const float* p0, const float* p1,
                                            float w0, float w1, ushort_t* dst) {
  float4 a0 = *(const float4*)p0;
  float4 a1 = *(const float4*)(p0 + 4);
  float4 b0 = *(const float4*)p1;
  float4 b1 = *(const float4*)(p1 + 4);
  uint4 o;
  o.x = pack2(w0 * a0.x + w1 * b0.x, w0 * a0.y + w1 * b0.y);
  o.y = pack2(w0 * a0.z + w1 * b0.z, w0 * a0.w + w1 * b0.w);
  o.z = pack2(w0 * a1.x + w1 * b1.x, w0 * a1.y + w1 * b1.y);
  o.w = pack2(w0 * a1.z + w1 * b1.z, w0 * a1.w + w1 * b1.w);
  *(uint4*)dst = o;
}
__device__ __forceinline__ void lerp8_store(const ushort_t* p0, const ushort_t* p1,
                                            float w0, float w1, ushort_t* dst) {
  uint4 a = *(const uint4*)p0;
  uint4 b = *(const uint4*)p1;
  uint_t aw[4] = {a.x, a.y, a.z, a.w};
  uint_t bw[4] = {b.x, b.y, b.z, b.w};
  uint_t pk[4];
#pragma unroll
  for (int e = 0; e < 4; ++e) {
    float a0 = b2f((ushort_t)(aw[e] & 0xffffu)), a1 = b2f((ushort_t)(aw[e] >> 16));
    float c0 = b2f((ushort_t)(bw[e] & 0xffffu)), c1 = b2f((ushort_t)(bw[e] >> 16));
    pk[e] = pack2(w0 * a0 + w1 * c0, w0 * a1 + w1 * c1);
  }
  uint4 o; o.x = pk[0]; o.y = pk[1]; o.z = pk[2]; o.w = pk[3];
  *(uint4*)dst = o;
}

// ---------------------------------------------------------------------------
// Runtime dtype probe: bf16 latent ~ N(0,1) -> all |v| < ~5. fp32 latent read
// as bf16 pairs -> low halves have random exponents -> huge/NaN values.
// flag = 1 -> inputs are fp32; flag = 0 -> inputs are bf16.
// ---------------------------------------------------------------------------
__global__ void detect_mode(const ushort_t* __restrict__ lat, int* __restrict__ flag) {
  if (threadIdx.x == 0) *flag = 0;
  __syncthreads();
  int big = 0;
  for (int i = threadIdx.x; i < 1024; i += 64) {
    float v = b2f(lat[i]);
    if (!(fabsf(v) < 1e5f)) big = 1;   // catches huge and NaN
  }
  if (__any(big) && threadIdx.x == 0) *flag = 1;
}

// ---------------------------------------------------------------------------
// Pack weights into MFMA B-fragment order (bf16):
//   pw[((kt*16 + nt)*64 + lane)*8 + j] = W[k][n],
//   k = kt*32 + (lane>>4)*8 + j, n = nt*16 + (lane&15)
// W0 gets the feature-row permutation (sampled(192) | coord | pe(12) | 0-pad)
// and zero-fill to K=224.
// ---------------------------------------------------------------------------
template <typename TI>
__global__ void pack_w_t(const TI* __restrict__ W0, const TI* __restrict__ W1,
                         const TI* __restrict__ W2, const TI* __restrict__ W3,
                         ushort_t* __restrict__ pw, const int* __restrict__ flag, int want)
{
  if (*flag != want) return;
  int g = blockIdx.x * blockDim.x + threadIdx.x;
  if (g >= 31 * 1024) return;
  int lane = g & 63;
  int nt   = (g >> 6) & 15;
  int ktg  = g >> 10;                       // 0..30
  const TI* W; ushort_t* dst; int kt; bool isw0 = false;
  if (ktg < 7)       { W = W0; dst = pw + PW0_OFF; kt = ktg;      isw0 = true; }
  else if (ktg < 15) { W = W1; dst = pw + PW1_OFF; kt = ktg - 7;  }
  else if (ktg < 23) { W = W2; dst = pw + PW2_OFF; kt = ktg - 15; }
  else               { W = W3; dst = pw + PW3_OFF; kt = ktg - 23; }
  int n  = nt * 16 + (lane & 15);
  int kb = kt * 32 + (lane >> 4) * 8;
  uint_t words[4];
#pragma unroll
  for (int h = 0; h < 4; ++h) {
    int k0 = kb + 2 * h, k1 = k0 + 1;
    ushort_t lo, hi;
    if (isw0) {
      // permuted feature order: k'<192 -> orig 13+k' (sampled); k'==192 -> orig 0
      // (coord); 193..204 -> orig k'-192 (pe); >=205 -> zero pad
      int ko0 = (k0 < 192) ? (13 + k0) : (k0 == 192 ? 0 : (k0 < 205 ? k0 - 192 : -1));
      int ko1 = (k1 < 192) ? (13 + k1) : (k1 == 192 ? 0 : (k1 < 205 ? k1 - 192 : -1));
      lo = (ko0 >= 0) ? f2b(ldv(W, (long)ko0 * 256 + n)) : (ushort_t)0;
      hi = (ko1 >= 0) ? f2b(ldv(W, (long)ko1 * 256 + n)) : (ushort_t)0;
    } else {
      lo = f2b(ldv(W, (long)k0 * 256 + n));
      hi = f2b(ldv(W, (long)k1 * 256 + n));
    }
    words[h] = (uint_t)lo | ((uint_t)hi << 16);
  }
  uint4 o; o.x = words[0]; o.y = words[1]; o.z = words[2]; o.w = words[3];
  *(uint4*)(dst + ((size_t)(kt * 16 + nt) * 64 + lane) * 8) = o;
}

// ---------------------------------------------------------------------------
// One 256-wide MLP layer, in place in LDS. 16 waves as 4x4 grid:
// wave (wr,wc) computes rows [wr*32,+32) x cols [wc*64,+64) -> acc[2][4],
// 32 accumulator VGPRs per lane (the R2->R3 fix: halves reg pressure, no spill).
// ---------------------------------------------------------------------------
template <typename TI>
__device__ __forceinline__ void mlp_layer(ushort_t* hb, const ushort_t* __restrict__ pw,
                                          const TI* __restrict__ bias,
                                          int ktiles, int wr, int wc, int lane)
{
  float4v acc[2][4];
#pragma unroll
  for (int rt = 0; rt < 2; ++rt)
#pragma unroll
    for (int nt = 0; nt < 4; ++nt)
      acc[rt][nt] = (float4v){0.f, 0.f, 0.f, 0.f};

  const int rsel = lane & 15;
  const int q8   = (lane >> 4) * 8;
  for (int kt = 0; kt < ktiles; ++kt) {
    short8 a[2], bfrag[4];
#pragma unroll
    for (int rt = 0; rt < 2; ++rt)
      a[rt] = *(const short8*)&hb[(wr * 32 + rt * 16 + rsel) * STRIDE + kt * 32 + q8];
#pragma unroll
    for (int nt = 0; nt < 4; ++nt)
      bfrag[nt] = *(const short8*)(pw + ((size_t)(kt * 16 + wc * 4 + nt) * 64 + lane) * 8);
#pragma unroll
    for (int rt = 0; rt < 2; ++rt)
#pragma unroll
      for (int nt = 0; nt < 4; ++nt)
        acc[rt][nt] = __builtin_amdgcn_mfma_f32_16x16x32_bf16(a[rt], bfrag[nt], acc[rt][nt], 0, 0, 0);
  }
  __syncthreads();   // all reads of hb for this layer done before in-place writes
#pragma unroll
  for (int nt = 0; nt < 4; ++nt) {
    int col = wc * 64 + nt * 16 + rsel;
    float bv = ldv(bias, col);
#pragma unroll
    for (int rt = 0; rt < 2; ++rt) {
      int rbase = wr * 32 + rt * 16 + (lane >> 4) * 4;
#pragma unroll
      for (int r = 0; r < 4; ++r) {
        float v = acc[rt][nt][r] + bv;
        v = fmaxf(v, 0.0f);
        hb[(rbase + r) * STRIDE + col] = f2b(v);
      }
    }
  }
  __syncthreads();
}

// ---------------------------------------------------------------------------
// Fused kernel: feature build -> 4 MFMA layers (in-place LDS) -> final dot
// 1024 threads/block, 128 points/block.
// ---------------------------------------------------------------------------
template <typename TI>
__global__ __launch_bounds__(1024, 4) void lisa_fused_t(
    const TI* __restrict__ coord, const TI* __restrict__ latent,
    const TI* __restrict__ bias0, const TI* __restrict__ bias1,
    const TI* __restrict__ bias2, const TI* __restrict__ bias3,
    const TI* __restrict__ W4,    const TI* __restrict__ b4,
    const ushort_t* __restrict__ pw, TI* __restrict__ out,
    const int* __restrict__ flag, int want)
{
  if (*flag != want) return;
  __shared__ ushort_t hb[128 * STRIDE];   // 67,584 B
  __shared__ float w4s[256];

  const int tid = threadIdx.x;
  const int row = tid >> 3;               // 0..127
  const int s   = tid & 7;                // 0..7
  const int p   = blockIdx.x * 128 + row;
  const int b   = p >> 15;                // / 32768

  if (tid < 256) w4s[tid] = ldv(W4, tid);

  // ---- feature build: hb[row][0..223] = [sampled(192) | coord | pe(12) | 0-pad]
  float c   = ldv(coord, p);
  float ix  = c * 2048.0f - 0.5f;
  float x0f = floorf(ix);
  float t   = ix - x0f;
  int   x0  = (int)x0f;
  int   i0  = imin(imax(x0, 0), NLAT - 1);
  int   i1  = imin(imax(x0 + 1, 0), NLAT - 1);
  const TI* lat = latent + (size_t)b * (NLAT * DLAT);
  float w0f = 1.0f - t, w1f = t;
  // 24 sub-chunks of 8 elems; thread s does sub-chunks s, s+8, s+16
#pragma unroll
  for (int j = 0; j < 3; ++j) {
    int cidx = s + 8 * j;
    int reg  = cidx >> 3;                 // 0: prev, 1: self, 2: next
    int off  = (cidx & 7) * 8;
    int r0 = (reg == 0) ? imax(i0 - 1, 0) : (reg == 1 ? i0 : imin(i0 + 1, NLAT - 1));
    int r1 = (reg == 0) ? imax(i1 - 1, 0) : (reg == 1 ? i1 : imin(i1 + 1, NLAT - 1));
    lerp8_store(lat + (long)r0 * DLAT + off, lat + (long)r1 * DLAT + off,
                w0f, w1f, &hb[row * STRIDE + reg * 64 + off]);
  }
  if (s == 0) {
    hb[row * STRIDE + 192] = f2b(c);
    float f = 1.0f;
#pragma unroll
    for (int k = 0; k < 6; ++k) {
      float ang = c * f;
      hb[row * STRIDE + 193 + 2 * k] = f2b(__sinf(ang));
      hb[row * STRIDE + 194 + 2 * k] = f2b(__cosf(ang));
      f *= 2.0f;
    }
  } else if (s == 1) {
    for (int k = 205; k < 224; ++k) hb[row * STRIDE + k] = 0;
  }
  __syncthreads();

  // ---- 4 hidden layers (16 waves, 4x4 wave grid) ----
  const int lane = tid & 63;
  const int wv   = tid >> 6;
  const int wr   = wv >> 2;   // 0..3
  const int wc   = wv & 3;    // 0..3
  mlp_layer(hb, pw + PW0_OFF, bias0, 7, wr, wc, lane);
  mlp_layer(hb, pw + PW1_OFF, bias1, 8, wr, wc, lane);
  mlp_layer(hb, pw + PW2_OFF, bias2, 8, wr, wc, lane);
  mlp_layer(hb, pw + PW3_OFF, bias3, 8, wr, wc, lane);

  // ---- final 256 -> 1 dot (fp32 VALU), 8 threads/row x 32 elems ----
  float partial = 0.f;
  const int kb = s * 32;
#pragma unroll
  for (int m = 0; m < 4; ++m) {
    uint4 hv = *(const uint4*)&hb[row * STRIDE + kb + m * 8];   // 8 bf16
    const float* wp = w4s + kb + m * 8;
    uint_t hw[4] = {hv.x, hv.y, hv.z, hv.w};
#pragma unroll
    for (int e = 0; e < 4; ++e) {
      partial += b2f((ushort_t)(hw[e] & 0xffffu)) * wp[2 * e];
      partial += b2f((ushort_t)(hw[e] >> 16))     * wp[2 * e + 1];
    }
  }
  partial += __shfl_xor(partial, 1, 64);
  partial += __shfl_xor(partial, 2, 64);
  partial += __shfl_xor(partial, 4, 64);
  if (s == 0) stv(out, p, partial + ldv(b4, 0));
}

extern "C" void kernel_launch(void* const* d_in, const int* in_sizes, int n_in,
                              void* d_out, int out_size, void* d_ws, size_t ws_size,
                              hipStream_t stream) {
  int* flag = (int*)d_ws;
  ushort_t* pw = (ushort_t*)d_ws + PW_BASE;

  detect_mode<<<1, 64, 0, stream>>>((const ushort_t*)d_in[1], flag);

  // fp32-input variant (flag==1)
  pack_w_t<float><<<62, 512, 0, stream>>>(
      (const float*)d_in[2], (const float*)d_in[4], (const float*)d_in[6],
      (const float*)d_in[8], pw, flag, 1);
  lisa_fused_t<float><<<2048, 1024, 0, stream>>>(
      (const float*)d_in[0], (const float*)d_in[1],
      (const float*)d_in[3], (const float*)d_in[5], (const float*)d_in[7],
      (const float*)d_in[9], (const float*)d_in[10], (const float*)d_in[11],
      pw, (float*)d_out, flag, 1);

  // bf16-input variant (flag==0)
  pack_w_t<ushort_t><<<62, 512, 0, stream>>>(
      (const ushort_t*)d_in[2], (const ushort_t*)d_in[4], (const ushort_t*)d_in[6],
      (const ushort_t*)d_in[8], pw, flag, 0);
  lisa_fused_t<ushort_t><<<2048, 1024, 0, stream>>>(
      (const ushort_t*)d_in[0], (const ushort_t*)d_in[1],
      (const ushort_t*)d_in[3], (const ushort_t*)d_in[5], (const ushort_t*)d_in[7],
      (const ushort_t*)d_in[9], (const ushort_t*)d_in[10], (const ushort_t*)d_in[11],
      pw, (ushort_t*)d_out, flag, 0);
}

// Round 6
// 327.010 us; speedup vs baseline: 1.0197x; 1.0197x over previous
//
#include <hip/hip_runtime.h>

typedef unsigned short ushort_t;
typedef unsigned int uint_t;
typedef __attribute__((ext_vector_type(8))) short short8;
typedef __attribute__((ext_vector_type(4))) float float4v;
typedef __attribute__((ext_vector_type(4))) uint_t uint4v;

#define NLAT 2048
#define DLAT 64

// d_ws layout (ushort units): [0..127] flag area (int at byte 0), then packed weights
#define PW_BASE 128
#define PW0_OFF 0        // layer0: KT=7 -> 7*16*64*8 = 57344 ushorts
#define PW1_OFF 57344    // KT=8 -> 65536 each
#define PW2_OFF 122880
#define PW3_OFF 188416

__device__ __forceinline__ float b2f(ushort_t u) {
  union { uint_t i; float f; } v; v.i = ((uint_t)u) << 16; return v.f;
}
__device__ __forceinline__ ushort_t f2b(float f) {
  uint_t x = __float_as_uint(f);
  uint_t r = (x + 0x7fffu + ((x >> 16) & 1u)) >> 16;   // RNE
  return (ushort_t)r;
}
__device__ __forceinline__ uint_t pack2(float lo, float hi) {
  return (uint_t)f2b(lo) | ((uint_t)f2b(hi) << 16);
}
__device__ __forceinline__ int imin(int a, int b) { return a < b ? a : b; }
__device__ __forceinline__ int imax(int a, int b) { return a > b ? a : b; }

__device__ __forceinline__ float ldv(const float* p, long i)    { return p[i]; }
__device__ __forceinline__ float ldv(const ushort_t* p, long i) { return b2f(p[i]); }
__device__ __forceinline__ void stv(float* p, long i, float v)    { p[i] = v; }
__device__ __forceinline__ void stv(ushort_t* p, long i, float v) { p[i] = f2b(v); }

// load 4 consecutive elements -> float4 (fp32: 16B; bf16: 8B)
__device__ __forceinline__ float4 load4f(const float* p) { return *(const float4*)p; }
__device__ __forceinline__ float4 load4f(const ushort_t* p) {
  uint2 u = *(const uint2*)p;
  float4 r;
  r.x = b2f((ushort_t)(u.x & 0xffffu)); r.y = b2f((ushort_t)(u.x >> 16));
  r.z = b2f((ushort_t)(u.y & 0xffffu)); r.w = b2f((ushort_t)(u.y >> 16));
  return r;
}

// ---------------------------------------------------------------------------
// Runtime dtype probe (same as R2/R3, proven): flag=1 -> fp32, flag=0 -> bf16
// ---------------------------------------------------------------------------
__global__ void detect_mode(const ushort_t* __restrict__ lat, int* __restrict__ flag) {
  if (threadIdx.x == 0) *flag = 0;
  __syncthreads();
  int big = 0;
  for (int i = threadIdx.x; i < 1024; i += 64) {
    float v = b2f(lat[i]);
    if (!(fabsf(v) < 1e5f)) big = 1;
  }
  if (__any(big) && threadIdx.x == 0) *flag = 1;
}

// ---------------------------------------------------------------------------
// Pack weights as MFMA *A*-fragments (A = W^T, m = chan_out) with the
// sigma k-permutation that matches the C-layout register order:
//   element j of frag(layer, mt, kt, lane) = W[sigma][mt*16 + (lane&15)]
//   sigma = 32*kt + 16*(j>>2) + 4*(lane>>4) + (j&3)
// Layer 0: sigma indexes the PERMUTED feature vector
//   [sampled(192) | coord | pe(12) | pad->224], mapped back to W0 rows.
// ---------------------------------------------------------------------------
template <typename TI>
__global__ void pack_w_t(const TI* __restrict__ W0, const TI* __restrict__ W1,
                         const TI* __restrict__ W2, const TI* __restrict__ W3,
                         ushort_t* __restrict__ pw, const int* __restrict__ flag, int want)
{
  if (*flag != want) return;
  int g = blockIdx.x * blockDim.x + threadIdx.x;
  if (g >= 31 * 1024) return;
  int lane = g & 63, q = lane >> 4;
  int mt   = (g >> 6) & 15;
  int ktg  = g >> 10;                       // 0..30
  const TI* W; ushort_t* dst; int kt, KT; bool isw0 = false;
  if (ktg < 7)       { W = W0; dst = pw + PW0_OFF; kt = ktg;      KT = 7; isw0 = true; }
  else if (ktg < 15) { W = W1; dst = pw + PW1_OFF; kt = ktg - 7;  KT = 8; }
  else if (ktg < 23) { W = W2; dst = pw + PW2_OFF; kt = ktg - 15; KT = 8; }
  else               { W = W3; dst = pw + PW3_OFF; kt = ktg - 23; KT = 8; }
  int col = mt * 16 + (lane & 15);
  uint_t words[4];
#pragma unroll
  for (int h = 0; h < 4; ++h) {
    ushort_t vv[2];
#pragma unroll
    for (int e = 0; e < 2; ++e) {
      int j = 2 * h + e;
      int f = 32 * kt + 16 * (j >> 2) + 4 * q + (j & 3);
      int row = f;
      if (isw0) row = (f < 192) ? (13 + f) : (f == 192 ? 0 : (f <= 204 ? f - 192 : -1));
      vv[e] = (row >= 0) ? f2b(ldv(W, (long)row * 256 + col)) : (ushort_t)0;
    }
    words[h] = (uint_t)vv[0] | ((uint_t)vv[1] << 16);
  }
  uint4 o; o.x = words[0]; o.y = words[1]; o.z = words[2]; o.w = words[3];
  *(uint4*)(dst + ((size_t)(mt * KT + kt) * 64 + lane) * 8) = o;
}

// ---------------------------------------------------------------------------
// Layer compute: acc[mt][g] += A(mt,kt) * hfrag[kt][g].
// mt<8 A-frags from LDS (imm-offset ds_read_b128), mt>=8 from global (L2-hot)
// -> balances LDS and VMEM pipes.
// ---------------------------------------------------------------------------
template <int KT>
__device__ __forceinline__ void compute_layer(float4v (&acc)[16][2],
                                              const uint4v (&hu)[8][2],
                                              const ushort_t* __restrict__ gsrc,
                                              const ushort_t* pwlds, int lane)
{
#pragma unroll
  for (int mt = 0; mt < 16; ++mt) {
    acc[mt][0] = (float4v){0.f, 0.f, 0.f, 0.f};
    acc[mt][1] = (float4v){0.f, 0.f, 0.f, 0.f};
  }
#pragma unroll
  for (int kt = 0; kt < KT; ++kt) {
    short8 b0 = __builtin_bit_cast(short8, hu[kt][0]);
    short8 b1 = __builtin_bit_cast(short8, hu[kt][1]);
#pragma unroll
    for (int mt = 0; mt < 16; ++mt) {
      short8 a;
      if (mt < 8) a = *(const short8*)&pwlds[((size_t)(mt * KT + kt) * 64 + lane) * 8];
      else        a = *(const short8*)&gsrc[((size_t)(mt * KT + kt) * 64 + lane) * 8];
      acc[mt][0] = __builtin_amdgcn_mfma_f32_16x16x32_bf16(a, b0, acc[mt][0], 0, 0, 0);
      acc[mt][1] = __builtin_amdgcn_mfma_f32_16x16x32_bf16(a, b1, acc[mt][1], 0, 0, 0);
    }
  }
}

// acc -> bias+relu+bf16 pack -> hfrag (B operand of next layer, sigma order)
__device__ __forceinline__ void convert_layer(float4v (&acc)[16][2], uint4v (&hu)[8][2],
                                              const float* bwl, int q)
{
#pragma unroll
  for (int mt = 0; mt < 16; ++mt) {
    float4 b4 = *(const float4*)&bwl[mt * 16 + 4 * q];
#pragma unroll
    for (int g = 0; g < 2; ++g) {
      float v0 = fmaxf(acc[mt][g][0] + b4.x, 0.f);
      float v1 = fmaxf(acc[mt][g][1] + b4.y, 0.f);
      float v2 = fmaxf(acc[mt][g][2] + b4.z, 0.f);
      float v3 = fmaxf(acc[mt][g][3] + b4.w, 0.f);
      hu[mt >> 1][g][(mt & 1) * 2 + 0] = pack2(v0, v1);
      hu[mt >> 1][g][(mt & 1) * 2 + 1] = pack2(v2, v3);
    }
  }
}

// ---------------------------------------------------------------------------
// Fused kernel. 512 threads = 8 waves; wave owns 32 points (2 groups of 16).
// Activations live in registers the whole way; LDS only holds weights/bias.
// ---------------------------------------------------------------------------
template <typename TI>
__global__ __launch_bounds__(512, 2) void lisa_fused_t(
    const TI* __restrict__ coord, const TI* __restrict__ latent,
    const TI* __restrict__ bias0, const TI* __restrict__ bias1,
    const TI* __restrict__ bias2, const TI* __restrict__ bias3,
    const TI* __restrict__ W4,    const TI* __restrict__ b4,
    const ushort_t* __restrict__ pw, TI* __restrict__ out,
    const int* __restrict__ flag, int want)
{
  if (*flag != want) return;
  __shared__ __align__(16) ushort_t pwlds[8 * 8 * 64 * 8];  // 64 KB: mt<8 half
  __shared__ __align__(16) float bw[4 * 256 + 256 + 1];     // biases | w4 | b4

  const int tid  = threadIdx.x;
  const int lane = tid & 63, q = lane >> 4, m15 = lane & 15;
  const int wv   = tid >> 6;
  const long pbase = (long)blockIdx.x * 256 + wv * 32 + m15;  // group g adds 16

  // ---- stage layer-0 LDS half + bias/w4 table ----
  {
    const uint4* s = (const uint4*)(pw + PW0_OFF);
    uint4* d = (uint4*)pwlds;
    for (int i = tid; i < 7 * 512; i += 512) d[i] = s[i];
  }
  for (int i = tid; i < 1281; i += 512) {
    float v;
    if (i < 256)       v = ldv(bias0, i);
    else if (i < 512)  v = ldv(bias1, i - 256);
    else if (i < 768)  v = ldv(bias2, i - 512);
    else if (i < 1024) v = ldv(bias3, i - 768);
    else if (i < 1280) v = ldv(W4, i - 1024);
    else               v = ldv(b4, 0);
    bw[i] = v;
  }

  // ---- feature build directly into sigma-ordered B-frags (registers) ----
  uint4v hu[8][2];
#pragma unroll
  for (int g = 0; g < 2; ++g) {
    long p = pbase + g * 16;
    float c   = ldv(coord, p);
    float ixv = c * 2048.0f - 0.5f;
    float x0f = floorf(ixv);
    float t   = ixv - x0f;
    int   x0  = (int)x0f;
    int   i0  = imin(imax(x0, 0), NLAT - 1);
    int   i1  = imin(imax(x0 + 1, 0), NLAT - 1);
    float w0 = 1.0f - t, w1 = t;
    int rows0[3] = { imax(i0 - 1, 0), i0, imin(i0 + 1, NLAT - 1) };
    int rows1[3] = { imax(i1 - 1, 0), i1, imin(i1 + 1, NLAT - 1) };
    const TI* lat = latent + (size_t)(p >> 15) * (NLAT * DLAT);
#pragma unroll
    for (int tb = 0; tb < 12; ++tb) {
      int region = tb >> 2;
      int d0 = 16 * (tb & 3) + 4 * q;
      float4 a = load4f(lat + (long)rows0[region] * DLAT + d0);
      float4 b = load4f(lat + (long)rows1[region] * DLAT + d0);
      float v0 = w0 * a.x + w1 * b.x;
      float v1 = w0 * a.y + w1 * b.y;
      float v2 = w0 * a.z + w1 * b.z;
      float v3 = w0 * a.w + w1 * b.w;
      hu[tb >> 1][g][(tb & 1) * 2 + 0] = pack2(v0, v1);
      hu[tb >> 1][g][(tb & 1) * 2 + 1] = pack2(v2, v3);
    }
    // t-block 12: channels 192+4q+s = [coord | pe0..pe11 | pad]; t-block 13: pad
    float pv[4];
#pragma unroll
    for (int s = 0; s < 4; ++s) {
      int f = 192 + 4 * q + s;
      float v = 0.0f;
      if (f == 192) v = c;
      else if (f <= 204) {
        int i = f - 193;
        float fr = (float)(1 << (i >> 1));
        float ang = c * fr;
        v = (i & 1) ? __cosf(ang) : __sinf(ang);
      }
      pv[s] = v;
    }
    hu[6][g][0] = pack2(pv[0], pv[1]);
    hu[6][g][1] = pack2(pv[2], pv[3]);
    hu[6][g][2] = 0; hu[6][g][3] = 0;
  }
  __syncthreads();

  float4v acc[16][2];

  // ---- layer 0 (K=224, KT=7) ----
  compute_layer<7>(acc, hu, pw + PW0_OFF, pwlds, lane);
  __syncthreads();
  convert_layer(acc, hu, bw + 0 * 256, q);
  {
    const uint4* s = (const uint4*)(pw + PW1_OFF);
    uint4* d = (uint4*)pwlds;
    for (int i = tid; i < 8 * 512; i += 512) d[i] = s[i];
  }
  __syncthreads();

  // ---- layer 1 ----
  compute_layer<8>(acc, hu, pw + PW1_OFF, pwlds, lane);
  __syncthreads();
  convert_layer(acc, hu, bw + 1 * 256, q);
  {
    const uint4* s = (const uint4*)(pw + PW2_OFF);
    uint4* d = (uint4*)pwlds;
    for (int i = tid; i < 8 * 512; i += 512) d[i] = s[i];
  }
  __syncthreads();

  // ---- layer 2 ----
  compute_layer<8>(acc, hu, pw + PW2_OFF, pwlds, lane);
  __syncthreads();
  convert_layer(acc, hu, bw + 2 * 256, q);
  {
    const uint4* s = (const uint4*)(pw + PW3_OFF);
    uint4* d = (uint4*)pwlds;
    for (int i = tid; i < 8 * 512; i += 512) d[i] = s[i];
  }
  __syncthreads();

  // ---- layer 3 ----
  compute_layer<8>(acc, hu, pw + PW3_OFF, pwlds, lane);

  // ---- final: bias3+relu fused with 256->1 dot against w4 ----
  float partial0 = 0.f, partial1 = 0.f;
#pragma unroll
  for (int mt = 0; mt < 16; ++mt) {
    float4 b3v = *(const float4*)&bw[3 * 256 + mt * 16 + 4 * q];
    float4 w4v = *(const float4*)&bw[1024 + mt * 16 + 4 * q];
    float v;
    v = fmaxf(acc[mt][0][0] + b3v.x, 0.f); partial0 += v * w4v.x;
    v = fmaxf(acc[mt][0][1] + b3v.y, 0.f); partial0 += v * w4v.y;
    v = fmaxf(acc[mt][0][2] + b3v.z, 0.f); partial0 += v * w4v.z;
    v = fmaxf(acc[mt][0][3] + b3v.w, 0.f); partial0 += v * w4v.w;
    v = fmaxf(acc[mt][1][0] + b3v.x, 0.f); partial1 += v * w4v.x;
    v = fmaxf(acc[mt][1][1] + b3v.y, 0.f); partial1 += v * w4v.y;
    v = fmaxf(acc[mt][1][2] + b3v.z, 0.f); partial1 += v * w4v.z;
    v = fmaxf(acc[mt][1][3] + b3v.w, 0.f); partial1 += v * w4v.w;
  }
  // sum the 4 quads holding this point's channels
  partial0 += __shfl_xor(partial0, 16, 64);
  partial0 += __shfl_xor(partial0, 32, 64);
  partial1 += __shfl_xor(partial1, 16, 64);
  partial1 += __shfl_xor(partial1, 32, 64);
  if (lane < 16) {
    float bb = bw[1280];
    stv(out, pbase,      partial0 + bb);
    stv(out, pbase + 16, partial1 + bb);
  }
}

extern "C" void kernel_launch(void* const* d_in, const int* in_sizes, int n_in,
                              void* d_out, int out_size, void* d_ws, size_t ws_size,
                              hipStream_t stream) {
  int* flag = (int*)d_ws;
  ushort_t* pw = (ushort_t*)d_ws + PW_BASE;

  detect_mode<<<1, 64, 0, stream>>>((const ushort_t*)d_in[1], flag);

  // fp32-input variant (flag==1)
  pack_w_t<float><<<62, 512, 0, stream>>>(
      (const float*)d_in[2], (const float*)d_in[4], (const float*)d_in[6],
      (const float*)d_in[8], pw, flag, 1);
  lisa_fused_t<float><<<1024, 512, 0, stream>>>(
      (const float*)d_in[0], (const float*)d_in[1],
      (const float*)d_in[3], (const float*)d_in[5], (const float*)d_in[7],
      (const float*)d_in[9], (const float*)d_in[10], (const float*)d_in[11],
      pw, (float*)d_out, flag, 1);

  // bf16-input variant (flag==0)
  pack_w_t<ushort_t><<<62, 512, 0, stream>>>(
      (const ushort_t*)d_in[2], (const ushort_t*)d_in[4], (const ushort_t*)d_in[6],
      (const ushort_t*)d_in[8], pw, flag, 0);
  lisa_fused_t<ushort_t><<<1024, 512, 0, stream>>>(
      (const ushort_t*)d_in[0], (const ushort_t*)d_in[1],
      (const ushort_t*)d_in[3], (const ushort_t*)d_in[5], (const ushort_t*)d_in[7],
      (const ushort_t*)d_in[9], (const ushort_t*)d_in[10], (const ushort_t*)d_in[11],
      pw, (ushort_t*)d_out, flag, 0);
}

// Round 7
// 258.583 us; speedup vs baseline: 1.2895x; 1.2646x over previous
//
#include <hip/hip_runtime.h>

typedef unsigned short ushort_t;
typedef unsigned int uint_t;
typedef __attribute__((ext_vector_type(8))) short short8;
typedef __attribute__((ext_vector_type(4))) float float4v;
typedef __attribute__((ext_vector_type(4))) uint_t uint4v;

#define NLAT 2048
#define DLAT 64

// d_ws layout (ushort units): [0..127] flag area (int at byte 0), then packed weights
#define PW_BASE 128
#define PW0_OFF 0        // layer0: KT=7 -> 7*16*64*8 = 57344 ushorts
#define PW1_OFF 57344    // KT=8 -> 65536 each
#define PW2_OFF 122880
#define PW3_OFF 188416
// half sizes (ushorts): mt 0-7 frags occupy KT*8*64*8 = KT*4096
#define H7 28672
#define H8 32768

__device__ __forceinline__ float b2f(ushort_t u) {
  union { uint_t i; float f; } v; v.i = ((uint_t)u) << 16; return v.f;
}
__device__ __forceinline__ ushort_t f2b(float f) {
  uint_t x = __float_as_uint(f);
  uint_t r = (x + 0x7fffu + ((x >> 16) & 1u)) >> 16;   // RNE
  return (ushort_t)r;
}
__device__ __forceinline__ uint_t pack2(float lo, float hi) {
  return (uint_t)f2b(lo) | ((uint_t)f2b(hi) << 16);
}
__device__ __forceinline__ int imin(int a, int b) { return a < b ? a : b; }
__device__ __forceinline__ int imax(int a, int b) { return a > b ? a : b; }

__device__ __forceinline__ float ldv(const float* p, long i)    { return p[i]; }
__device__ __forceinline__ float ldv(const ushort_t* p, long i) { return b2f(p[i]); }
__device__ __forceinline__ void stv(float* p, long i, float v)    { p[i] = v; }
__device__ __forceinline__ void stv(ushort_t* p, long i, float v) { p[i] = f2b(v); }

__device__ __forceinline__ float4 load4f(const float* p) { return *(const float4*)p; }
__device__ __forceinline__ float4 load4f(const ushort_t* p) {
  uint2 u = *(const uint2*)p;
  float4 r;
  r.x = b2f((ushort_t)(u.x & 0xffffu)); r.y = b2f((ushort_t)(u.x >> 16));
  r.z = b2f((ushort_t)(u.y & 0xffffu)); r.w = b2f((ushort_t)(u.y >> 16));
  return r;
}

// async 16B/lane global->LDS copy (gfx950 global_load_lds_dwordx4)
__device__ __forceinline__ void async_copy16(const ushort_t* g, ushort_t* l) {
  __builtin_amdgcn_global_load_lds(
      (const __attribute__((address_space(1))) void*)g,
      (__attribute__((address_space(3))) void*)l, 16, 0, 0);
}
// stage `chunks`*8KB from src(global, frag-packed) to dst(LDS), 512 threads
__device__ __forceinline__ void stage_half(ushort_t* dst, const ushort_t* src,
                                           int chunks, int tid) {
  for (int k = 0; k < chunks; ++k) {
    int i = tid + (k << 9);
    async_copy16(src + (size_t)i * 8, dst + (size_t)i * 8);
  }
}

// ---------------------------------------------------------------------------
// Runtime dtype probe: flag=1 -> fp32 inputs, flag=0 -> bf16
// ---------------------------------------------------------------------------
__global__ void detect_mode(const ushort_t* __restrict__ lat, int* __restrict__ flag) {
  if (threadIdx.x == 0) *flag = 0;
  __syncthreads();
  int big = 0;
  for (int i = threadIdx.x; i < 1024; i += 64) {
    float v = b2f(lat[i]);
    if (!(fabsf(v) < 1e5f)) big = 1;
  }
  if (__any(big) && threadIdx.x == 0) *flag = 1;
}

// ---------------------------------------------------------------------------
// Pack weights as MFMA A-fragments (A = W^T, m = chan_out), sigma k-permuted
// to match the C-register order of the previous layer:
//   element j of frag(mt,kt,lane) = W[sigma][mt*16 + (lane&15)]
//   sigma = 32*kt + 16*(j>>2) + 4*(lane>>4) + (j&3)
// Layer 0: sigma indexes [sampled(192) | coord | pe(12) | pad->224].
// ---------------------------------------------------------------------------
template <typename TI>
__global__ void pack_w_t(const TI* __restrict__ W0, const TI* __restrict__ W1,
                         const TI* __restrict__ W2, const TI* __restrict__ W3,
                         ushort_t* __restrict__ pw, const int* __restrict__ flag, int want)
{
  if (*flag != want) return;
  int g = blockIdx.x * blockDim.x + threadIdx.x;
  if (g >= 31 * 1024) return;
  int lane = g & 63, q = lane >> 4;
  int mt   = (g >> 6) & 15;
  int ktg  = g >> 10;                       // 0..30
  const TI* W; ushort_t* dst; int kt, KT; bool isw0 = false;
  if (ktg < 7)       { W = W0; dst = pw + PW0_OFF; kt = ktg;      KT = 7; isw0 = true; }
  else if (ktg < 15) { W = W1; dst = pw + PW1_OFF; kt = ktg - 7;  KT = 8; }
  else if (ktg < 23) { W = W2; dst = pw + PW2_OFF; kt = ktg - 15; KT = 8; }
  else               { W = W3; dst = pw + PW3_OFF; kt = ktg - 23; KT = 8; }
  int col = mt * 16 + (lane & 15);
  uint_t words[4];
#pragma unroll
  for (int h = 0; h < 4; ++h) {
    ushort_t vv[2];
#pragma unroll
    for (int e = 0; e < 2; ++e) {
      int j = 2 * h + e;
      int f = 32 * kt + 16 * (j >> 2) + 4 * q + (j & 3);
      int row = f;
      if (isw0) row = (f < 192) ? (13 + f) : (f == 192 ? 0 : (f <= 204 ? f - 192 : -1));
      vv[e] = (row >= 0) ? f2b(ldv(W, (long)row * 256 + col)) : (ushort_t)0;
    }
    words[h] = (uint_t)vv[0] | ((uint_t)vv[1] << 16);
  }
  uint4 o; o.x = words[0]; o.y = words[1]; o.z = words[2]; o.w = words[3];
  *(uint4*)(dst + ((size_t)(mt * KT + kt) * 64 + lane) * 8) = o;
}

// ---------------------------------------------------------------------------
// Compute one half-layer (8 mt tiles) entirely from LDS: pure ds_read_b128 ->
// MFMA loop (m97 shape). buf holds frags for mt in [MTBASE, MTBASE+8).
// ---------------------------------------------------------------------------
template <int KT, int MTBASE>
__device__ __forceinline__ void compute_half(float4v (&acc)[16][2],
                                             const uint4v (&hu)[8][2],
                                             const ushort_t* buf, int lane)
{
#pragma unroll
  for (int m = 0; m < 8; ++m) {
    acc[MTBASE + m][0] = (float4v){0.f, 0.f, 0.f, 0.f};
    acc[MTBASE + m][1] = (float4v){0.f, 0.f, 0.f, 0.f};
  }
#pragma unroll
  for (int kt = 0; kt < KT; ++kt) {
    short8 b0 = __builtin_bit_cast(short8, hu[kt][0]);
    short8 b1 = __builtin_bit_cast(short8, hu[kt][1]);
#pragma unroll
    for (int m = 0; m < 8; ++m) {
      short8 a = *(const short8*)&buf[((size_t)(m * KT + kt) * 64 + lane) * 8];
      acc[MTBASE + m][0] = __builtin_amdgcn_mfma_f32_16x16x32_bf16(a, b0, acc[MTBASE + m][0], 0, 0, 0);
      acc[MTBASE + m][1] = __builtin_amdgcn_mfma_f32_16x16x32_bf16(a, b1, acc[MTBASE + m][1], 0, 0, 0);
    }
  }
}

// acc -> bias+relu+bf16 pack -> hu (B operand of next layer, sigma order)
__device__ __forceinline__ void convert_layer(float4v (&acc)[16][2], uint4v (&hu)[8][2],
                                              const float* bwl, int q)
{
#pragma unroll
  for (int mt = 0; mt < 16; ++mt) {
    float4 b4 = *(const float4*)&bwl[mt * 16 + 4 * q];
#pragma unroll
    for (int g = 0; g < 2; ++g) {
      float v0 = fmaxf(acc[mt][g][0] + b4.x, 0.f);
      float v1 = fmaxf(acc[mt][g][1] + b4.y, 0.f);
      float v2 = fmaxf(acc[mt][g][2] + b4.z, 0.f);
      float v3 = fmaxf(acc[mt][g][3] + b4.w, 0.f);
      hu[mt >> 1][g][(mt & 1) * 2 + 0] = pack2(v0, v1);
      hu[mt >> 1][g][(mt & 1) * 2 + 1] = pack2(v2, v3);
    }
  }
}

// ---------------------------------------------------------------------------
// Fused kernel. 512 threads = 8 waves; wave owns 32 points (2 groups of 16).
// Activations in registers; weights ping-pong through two 64KB LDS buffers
// staged asynchronously with global_load_lds one half ahead of compute.
// ---------------------------------------------------------------------------
template <typename TI>
__global__ __launch_bounds__(512, 2) void lisa_fused_t(
    const TI* __restrict__ coord, const TI* __restrict__ latent,
    const TI* __restrict__ bias0, const TI* __restrict__ bias1,
    const TI* __restrict__ bias2, const TI* __restrict__ bias3,
    const TI* __restrict__ W4,    const TI* __restrict__ b4,
    const ushort_t* __restrict__ pw, TI* __restrict__ out,
    const int* __restrict__ flag, int want)
{
  if (*flag != want) return;
  __shared__ __align__(16) ushort_t wbuf[2][H8];         // 2 x 64 KB
  __shared__ __align__(16) float bw[4 * 256 + 256 + 1];  // biases | w4 | b4

  const int tid  = threadIdx.x;
  const int lane = tid & 63, q = lane >> 4, m15 = lane & 15;
  const int wv   = tid >> 6;
  const long pbase = (long)blockIdx.x * 256 + wv * 32 + m15;  // group g adds 16

  // ---- stage L0 half0 (async) + bias/w4 table ----
  stage_half(wbuf[0], pw + PW0_OFF, 7, tid);
  for (int i = tid; i < 1281; i += 512) {
    float v;
    if (i < 256)       v = ldv(bias0, i);
    else if (i < 512)  v = ldv(bias1, i - 256);
    else if (i < 768)  v = ldv(bias2, i - 512);
    else if (i < 1024) v = ldv(bias3, i - 768);
    else if (i < 1280) v = ldv(W4, i - 1024);
    else               v = ldv(b4, 0);
    bw[i] = v;
  }

  // ---- feature build directly into sigma-ordered B-frags (registers) ----
  uint4v hu[8][2];
#pragma unroll
  for (int g = 0; g < 2; ++g) {
    long p = pbase + g * 16;
    float c   = ldv(coord, p);
    float ixv = c * 2048.0f - 0.5f;
    float x0f = floorf(ixv);
    float t   = ixv - x0f;
    int   x0  = (int)x0f;
    int   i0  = imin(imax(x0, 0), NLAT - 1);
    int   i1  = imin(imax(x0 + 1, 0), NLAT - 1);
    float w0 = 1.0f - t, w1 = t;
    int rows0[3] = { imax(i0 - 1, 0), i0, imin(i0 + 1, NLAT - 1) };
    int rows1[3] = { imax(i1 - 1, 0), i1, imin(i1 + 1, NLAT - 1) };
    const TI* lat = latent + (size_t)(p >> 15) * (NLAT * DLAT);
#pragma unroll
    for (int tb = 0; tb < 12; ++tb) {
      int region = tb >> 2;
      int d0 = 16 * (tb & 3) + 4 * q;
      float4 a = load4f(lat + (long)rows0[region] * DLAT + d0);
      float4 b = load4f(lat + (long)rows1[region] * DLAT + d0);
      hu[tb >> 1][g][(tb & 1) * 2 + 0] = pack2(w0 * a.x + w1 * b.x, w0 * a.y + w1 * b.y);
      hu[tb >> 1][g][(tb & 1) * 2 + 1] = pack2(w0 * a.z + w1 * b.z, w0 * a.w + w1 * b.w);
    }
    float pv[4];
#pragma unroll
    for (int s = 0; s < 4; ++s) {
      int f = 192 + 4 * q + s;
      float v = 0.0f;
      if (f == 192) v = c;
      else if (f <= 204) {
        int i = f - 193;
        float fr = (float)(1 << (i >> 1));
        float ang = c * fr;
        v = (i & 1) ? __cosf(ang) : __sinf(ang);
      }
      pv[s] = v;
    }
    hu[6][g][0] = pack2(pv[0], pv[1]);
    hu[6][g][1] = pack2(pv[2], pv[3]);
    hu[6][g][2] = 0; hu[6][g][3] = 0;
  }
  __syncthreads();   // wbuf[0] ready (vmcnt drained), table ready

  float4v acc[16][2];

  // ---- layer 0 (KT=7) ----
  stage_half(wbuf[1], pw + PW0_OFF + H7, 7, tid);
  compute_half<7, 0>(acc, hu, wbuf[0], lane);
  __syncthreads();                                   // wbuf[1] ready, wbuf[0] free
  stage_half(wbuf[0], pw + PW1_OFF, 8, tid);
  compute_half<7, 8>(acc, hu, wbuf[1], lane);
  convert_layer(acc, hu, bw + 0 * 256, q);
  __syncthreads();

  // ---- layer 1 ----
  stage_half(wbuf[1], pw + PW1_OFF + H8, 8, tid);
  compute_half<8, 0>(acc, hu, wbuf[0], lane);
  __syncthreads();
  stage_half(wbuf[0], pw + PW2_OFF, 8, tid);
  compute_half<8, 8>(acc, hu, wbuf[1], lane);
  convert_layer(acc, hu, bw + 1 * 256, q);
  __syncthreads();

  // ---- layer 2 ----
  stage_half(wbuf[1], pw + PW2_OFF + H8, 8, tid);
  compute_half<8, 0>(acc, hu, wbuf[0], lane);
  __syncthreads();
  stage_half(wbuf[0], pw + PW3_OFF, 8, tid);
  compute_half<8, 8>(acc, hu, wbuf[1], lane);
  convert_layer(acc, hu, bw + 2 * 256, q);
  __syncthreads();

  // ---- layer 3 ----
  stage_half(wbuf[1], pw + PW3_OFF + H8, 8, tid);
  compute_half<8, 0>(acc, hu, wbuf[0], lane);
  __syncthreads();
  compute_half<8, 8>(acc, hu, wbuf[1], lane);

  // ---- final: bias3+relu fused with 256->1 dot against w4 ----
  float partial0 = 0.f, partial1 = 0.f;
#pragma unroll
  for (int mt = 0; mt < 16; ++mt) {
    float4 b3v = *(const float4*)&bw[3 * 256 + mt * 16 + 4 * q];
    float4 w4v = *(const float4*)&bw[1024 + mt * 16 + 4 * q];
    float v;
    v = fmaxf(acc[mt][0][0] + b3v.x, 0.f); partial0 += v * w4v.x;
    v = fmaxf(acc[mt][0][1] + b3v.y, 0.f); partial0 += v * w4v.y;
    v = fmaxf(acc[mt][0][2] + b3v.z, 0.f); partial0 += v * w4v.z;
    v = fmaxf(acc[mt][0][3] + b3v.w, 0.f); partial0 += v * w4v.w;
    v = fmaxf(acc[mt][1][0] + b3v.x, 0.f); partial1 += v * w4v.x;
    v = fmaxf(acc[mt][1][1] + b3v.y, 0.f); partial1 += v * w4v.y;
    v = fmaxf(acc[mt][1][2] + b3v.z, 0.f); partial1 += v * w4v.z;
    v = fmaxf(acc[mt][1][3] + b3v.w, 0.f); partial1 += v * w4v.w;
  }
  partial0 += __shfl_xor(partial0, 16, 64);
  partial0 += __shfl_xor(partial0, 32, 64);
  partial1 += __shfl_xor(partial1, 16, 64);
  partial1 += __shfl_xor(partial1, 32, 64);
  if (lane < 16) {
    float bb = bw[1280];
    stv(out, pbase,      partial0 + bb);
    stv(out, pbase + 16, partial1 + bb);
  }
}

extern "C" void kernel_launch(void* const* d_in, const int* in_sizes, int n_in,
                              void* d_out, int out_size, void* d_ws, size_t ws_size,
                              hipStream_t stream) {
  int* flag = (int*)d_ws;
  ushort_t* pw = (ushort_t*)d_ws + PW_BASE;

  detect_mode<<<1, 64, 0, stream>>>((const ushort_t*)d_in[1], flag);

  // fp32-input variant (flag==1)
  pack_w_t<float><<<62, 512, 0, stream>>>(
      (const float*)d_in[2], (const float*)d_in[4], (const float*)d_in[6],
      (const float*)d_in[8], pw, flag, 1);
  lisa_fused_t<float><<<1024, 512, 0, stream>>>(
      (const float*)d_in[0], (const float*)d_in[1],
      (const float*)d_in[3], (const float*)d_in[5], (const float*)d_in[7],
      (const float*)d_in[9], (const float*)d_in[10], (const float*)d_in[11],
      pw, (float*)d_out, flag, 1);

  // bf16-input variant (flag==0)
  pack_w_t<ushort_t><<<62, 512, 0, stream>>>(
      (const ushort_t*)d_in[2], (const ushort_t*)d_in[4], (const ushort_t*)d_in[6],
      (const ushort_t*)d_in[8], pw, flag, 0);
  lisa_fused_t<ushort_t><<<1024, 512, 0, stream>>>(
      (const ushort_t*)d_in[0], (const ushort_t*)d_in[1],
      (const ushort_t*)d_in[3], (const ushort_t*)d_in[5], (const ushort_t*)d_in[7],
      (const ushort_t*)d_in[9], (const ushort_t*)d_in[10], (const ushort_t*)d_in[11],
      pw, (ushort_t*)d_out, flag, 0);
}